// Round 1
// baseline (397.042 us; speedup 1.0000x reference)
//
#include <hip/hip_runtime.h>
#include <stdint.h>

// CycleFC 1w1a: out[b,o,h,w] = sum_c sign(x)[b,c,h,w+off(c)] * sign(W)[o,c] + bias[o]
// off(c) = (c+3)%7 - 3, zero-pad OOB. B=64, C=O=384, H=W=32.
//
// Binary-GEMM formulation: pack signs (bit=1 iff value<0) into 6 uint64 words
// (384 channels). product(+1/-1) match iff bits equal, so
//   sum = Nvalid - 2*popc((G ^ WB) & V)
// G = gathered x-sign bits (invalid bits forced 0), V = validity mask.
// popc((G^WB)&V) = popc(G^WB) - popc(WB & ~V)  (G==0 on ~V)
//   => out = bias2[o][w] - 2*popc(G^WB),  bias2 = bias + Nvalid(w) + 2*popc(WB&~V(w))
//
// Offset pattern periodic mod 7 in c; 64 % 7 == 1 so channel mask for offset d
// within 64-bit word j is P[(d - j) mod 7] where P[t] = bits k with k%7==t.

#define IN_CH 384
#define HH 32
#define WW 32
#define BB 64

constexpr uint64_t P7(int t) {
  uint64_t m = 0;
  for (int k = 0; k < 64; ++k)
    if (k % 7 == t) m |= (1ull << k);
  return m;
}
__device__ __constant__ uint64_t Pm[7] = {P7(0), P7(1), P7(2), P7(3), P7(4), P7(5), P7(6)};

// ---------------- prep: pack sign(W) and build bias2[o][w] table -------------
__global__ __launch_bounds__(384) void cyc_prep(const float* __restrict__ wgt,
                                                const float* __restrict__ bias,
                                                uint64_t* __restrict__ wbg,
                                                float* __restrict__ bias2) {
  __shared__ uint64_t sh_WB[IN_CH * 6];
  const int t = threadIdx.x;
  const int wave = t >> 6, lane = t & 63;
  const int c = (wave << 6) + lane;
  // pack: wave j packs word j (channels 64j..64j+63) for every o via ballot
  for (int o = 0; o < IN_CH; ++o) {
    uint64_t m = __ballot(wgt[o * IN_CH + c] < 0.0f);
    if (lane == 0) {
      sh_WB[o * 6 + wave] = m;
      wbg[o * 6 + wave] = m;
    }
  }
  __syncthreads();
  // bias2: thread o handles all 32 w
  const int o = t;
  uint64_t wb[6];
#pragma unroll
  for (int j = 0; j < 6; ++j) wb[j] = sh_WB[o * 6 + j];
  const float bo = bias[o];
  for (int w = 0; w < WW; ++w) {
    int nv = 0, corr = 0;
#pragma unroll
    for (int j = 0; j < 6; ++j) {
      uint64_t V = 0;
#pragma unroll
      for (int d = -3; d <= 3; ++d) {
        int wd = w + d;
        if (wd >= 0 && wd < WW) V |= Pm[(d - j + 14) % 7];
      }
      nv += __popcll(V);
      corr += __popcll(wb[j] & ~V);
    }
    bias2[o * WW + w] = bo + (float)nv + 2.0f * (float)corr;
  }
}

// ---------------- main: one block per (b,h) row ------------------------------
__global__ __launch_bounds__(384) void cyc_main(const float* __restrict__ x,
                                                const uint64_t* __restrict__ wbg,
                                                const float* __restrict__ bias2,
                                                float* __restrict__ out) {
  __shared__ uint64_t sh_WB[IN_CH * 6];   // 18432 B
  __shared__ uint64_t sh_X[WW][6];        // unshifted sign bits per w
  __shared__ uint64_t sh_G[WW][6];        // shifted+masked gather bits per w
  const int t = threadIdx.x;
  const int b = blockIdx.x >> 5;
  const int h = blockIdx.x & 31;

  // stage packed weights into LDS (coalesced, L2-resident after first touch)
  for (int i = t; i < IN_CH * 6; i += 384) sh_WB[i] = wbg[i];

  // ---- phase 1: pack x signs. lane = channel-within-word; each lane owns one
  // 128B cache line (its channel's w-row), builds a 32-bit sign word, then a
  // 32-ballot bit-transpose produces sh_X[w][wave].
  const int wave = t >> 6, lane = t & 63;
  const int c = (wave << 6) + lane;
  const float4* xp =
      reinterpret_cast<const float4*>(x + (size_t)((b * IN_CH + c) * HH + h) * WW);
  unsigned myw = 0;
#pragma unroll
  for (int i = 0; i < 8; ++i) {
    float4 v = xp[i];
    myw |= (v.x < 0.0f ? 1u : 0u) << (i * 4 + 0);
    myw |= (v.y < 0.0f ? 1u : 0u) << (i * 4 + 1);
    myw |= (v.z < 0.0f ? 1u : 0u) << (i * 4 + 2);
    myw |= (v.w < 0.0f ? 1u : 0u) << (i * 4 + 3);
  }
#pragma unroll
  for (int w = 0; w < WW; ++w) {
    uint64_t m = __ballot((myw >> w) & 1u);
    if (lane == 0) sh_X[w][wave] = m;
  }
  __syncthreads();

  // ---- phase 1.5: build G[w][j] = OR_d (X[w+d][j] & P[(d-j) mod 7])
  if (t < WW * 6) {
    const int w = t & 31, j = t >> 5;
    uint64_t g = 0;
#pragma unroll
    for (int d = -3; d <= 3; ++d) {
      int wd = w + d;
      if (wd >= 0 && wd < WW) g |= sh_X[wd][j] & Pm[(d - j + 14) % 7];
    }
    sh_G[w][j] = g;
  }
  __syncthreads();

  // ---- phase 2: 12 o-groups x 32 w threads; each thread does 32 outputs.
  const int w = t & 31, og = t >> 5;
  const uint64_t g0 = sh_G[w][0], g1 = sh_G[w][1], g2 = sh_G[w][2];
  const uint64_t g3 = sh_G[w][3], g4 = sh_G[w][4], g5 = sh_G[w][5];
  float* op = out + (size_t)b * (IN_CH * HH * WW) + (size_t)(og * 32) * (HH * WW) +
              h * WW + w;
  const float* bp = bias2 + (og * 32) * WW + w;
  const uint64_t* wbp = &sh_WB[(og * 32) * 6];
#pragma unroll 4
  for (int i = 0; i < 32; ++i) {
    int mm = __popcll(g0 ^ wbp[i * 6 + 0]) + __popcll(g1 ^ wbp[i * 6 + 1]) +
             __popcll(g2 ^ wbp[i * 6 + 2]) + __popcll(g3 ^ wbp[i * 6 + 3]) +
             __popcll(g4 ^ wbp[i * 6 + 4]) + __popcll(g5 ^ wbp[i * 6 + 5]);
    op[i * (HH * WW)] = bp[i * WW] - 2.0f * (float)mm;
  }
}

extern "C" void kernel_launch(void* const* d_in, const int* in_sizes, int n_in,
                              void* d_out, int out_size, void* d_ws, size_t ws_size,
                              hipStream_t stream) {
  const float* x = (const float*)d_in[0];
  const float* wgt = (const float*)d_in[1];
  const float* bias = (const float*)d_in[2];
  float* out = (float*)d_out;

  uint64_t* wbg = (uint64_t*)d_ws;                                    // 18432 B
  float* bias2 = (float*)((char*)d_ws + IN_CH * 6 * sizeof(uint64_t));  // 49152 B

  cyc_prep<<<1, 384, 0, stream>>>(wgt, bias, wbg, bias2);
  cyc_main<<<BB * HH, 384, 0, stream>>>(x, wbg, bias2, out);
}

// Round 2
// 216.362 us; speedup vs baseline: 1.8351x; 1.8351x over previous
//
#include <hip/hip_runtime.h>
#include <stdint.h>

// CycleFC 1w1a: out[b,o,h,w] = sum_c sign(x)[b,c,h,w+off(c)] * sign(W)[o,c] + bias[o]
// off(c) = (c+3)%7 - 3, zero-pad OOB. B=64, C=O=384, H=W=32.
//
// Binary-GEMM formulation: pack signs (bit=1 iff value<0) into 6 uint64 words
// (384 channels). product(+1/-1) match iff bits equal, so
//   sum = Nvalid - 2*popc((G ^ WB) & V)
// G = gathered x-sign bits (invalid bits forced 0), V = validity mask.
// popc((G^WB)&V) = popc(G^WB) - popc(WB & ~V)  (G==0 on ~V)
//   => out = bias2[o][w] - 2*popc(G^WB),  bias2 = bias + Nvalid(w) + 2*popc(WB&~V(w))
//
// Offset pattern periodic mod 7 in c; 64 % 7 == 1 so channel mask for offset d
// within 64-bit word j is P[(d - j) mod 7] where P[t] = bits k with k%7==t.

#define IN_CH 384
#define HH 32
#define WW 32
#define BB 64

constexpr uint64_t P7(int t) {
  uint64_t m = 0;
  for (int k = 0; k < 64; ++k)
    if (k % 7 == t) m |= (1ull << k);
  return m;
}
__device__ __constant__ uint64_t Pm[7] = {P7(0), P7(1), P7(2), P7(3), P7(4), P7(5), P7(6)};

// ---------------- prep: one block per output channel o ----------------------
// R1: was 1 block x 384 threads looping 384 ballots serially -> 197us
// latency-bound on one CU. Now 384 blocks x 64 threads (1 wave): 6 ballots
// each, fully parallel.
__global__ __launch_bounds__(64) void cyc_prep(const float* __restrict__ wgt,
                                               const float* __restrict__ bias,
                                               uint64_t* __restrict__ wbg,
                                               float* __restrict__ bias2) {
  const int o = blockIdx.x;
  const int lane = threadIdx.x;
  __shared__ uint64_t wb_sh[6];
#pragma unroll
  for (int j = 0; j < 6; ++j) {
    uint64_t m = __ballot(wgt[o * IN_CH + j * 64 + lane] < 0.0f);
    if (lane == 0) wb_sh[j] = m;
  }
  __syncthreads();
  if (lane < 6) wbg[o * 6 + lane] = wb_sh[lane];
  if (lane < WW) {
    const int w = lane;
    int nv = 0, corr = 0;
#pragma unroll
    for (int j = 0; j < 6; ++j) {
      uint64_t V = 0;
#pragma unroll
      for (int d = -3; d <= 3; ++d) {
        int wd = w + d;
        if (wd >= 0 && wd < WW) V |= Pm[(d - j + 14) % 7];
      }
      nv += __popcll(V);
      corr += __popcll(wb_sh[j] & ~V);
    }
    bias2[o * WW + w] = bias[o] + (float)nv + 2.0f * (float)corr;
  }
}

// ---------------- main: one block per (b,h) row ------------------------------
__global__ __launch_bounds__(384) void cyc_main(const float* __restrict__ x,
                                                const uint64_t* __restrict__ wbg,
                                                const float* __restrict__ bias2,
                                                float* __restrict__ out) {
  __shared__ __align__(16) uint64_t sh_WB[IN_CH * 6];  // 18432 B
  __shared__ uint64_t sh_X[WW][6];  // unshifted sign bits per w
  __shared__ uint64_t sh_G[WW][6];  // shifted+masked gather bits per w
  const int t = threadIdx.x;
  const int b = blockIdx.x >> 5;
  const int h = blockIdx.x & 31;

  // stage packed weights into LDS, float4-vectorized (1152 x 16B)
  {
    const float4* src = reinterpret_cast<const float4*>(wbg);
    float4* dst = reinterpret_cast<float4*>(sh_WB);
#pragma unroll
    for (int i = 0; i < 3; ++i) dst[t + i * 384] = src[t + i * 384];
  }

  // ---- phase 1: pack x signs. lane = channel-within-word; each lane owns one
  // 128B cache line (its channel's w-row), builds a 32-bit sign word, then a
  // 32-ballot bit-transpose produces sh_X[w][wave].
  const int wave = t >> 6, lane = t & 63;
  const int c = (wave << 6) + lane;
  const float4* xp =
      reinterpret_cast<const float4*>(x + (size_t)((b * IN_CH + c) * HH + h) * WW);
  unsigned myw = 0;
#pragma unroll
  for (int i = 0; i < 8; ++i) {
    float4 v = xp[i];
    myw |= (v.x < 0.0f ? 1u : 0u) << (i * 4 + 0);
    myw |= (v.y < 0.0f ? 1u : 0u) << (i * 4 + 1);
    myw |= (v.z < 0.0f ? 1u : 0u) << (i * 4 + 2);
    myw |= (v.w < 0.0f ? 1u : 0u) << (i * 4 + 3);
  }
#pragma unroll
  for (int w = 0; w < WW; ++w) {
    uint64_t m = __ballot((myw >> w) & 1u);
    if (lane == 0) sh_X[w][wave] = m;
  }
  __syncthreads();

  // ---- phase 1.5: build G[w][j] = OR_d (X[w+d][j] & P[(d-j) mod 7])
  if (t < WW * 6) {
    const int w = t & 31, j = t >> 5;
    uint64_t g = 0;
#pragma unroll
    for (int d = -3; d <= 3; ++d) {
      int wd = w + d;
      if (wd >= 0 && wd < WW) g |= sh_X[wd][j] & Pm[(d - j + 14) % 7];
    }
    sh_G[w][j] = g;
  }
  __syncthreads();

  // ---- phase 2: 12 o-groups x 32 w threads; each thread does 32 outputs.
  // Weight reads as 3x ds_read_b128 (48B per o, 16B-aligned since 48%16==0),
  // broadcast across the 32 lanes of an og group.
  const int w = t & 31, og = t >> 5;
  const uint64_t g0 = sh_G[w][0], g1 = sh_G[w][1], g2 = sh_G[w][2];
  const uint64_t g3 = sh_G[w][3], g4 = sh_G[w][4], g5 = sh_G[w][5];
  float* op = out + (size_t)b * (IN_CH * HH * WW) + (size_t)(og * 32) * (HH * WW) +
              h * WW + w;
  const float* bp = bias2 + (og * 32) * WW + w;
  const ulonglong2* wv = reinterpret_cast<const ulonglong2*>(&sh_WB[(og * 32) * 6]);
#pragma unroll 4
  for (int i = 0; i < 32; ++i) {
    ulonglong2 q0 = wv[i * 3 + 0];
    ulonglong2 q1 = wv[i * 3 + 1];
    ulonglong2 q2 = wv[i * 3 + 2];
    int mm = __popcll(g0 ^ q0.x) + __popcll(g1 ^ q0.y) + __popcll(g2 ^ q1.x) +
             __popcll(g3 ^ q1.y) + __popcll(g4 ^ q2.x) + __popcll(g5 ^ q2.y);
    op[i * (HH * WW)] = bp[i * WW] - 2.0f * (float)mm;
  }
}

extern "C" void kernel_launch(void* const* d_in, const int* in_sizes, int n_in,
                              void* d_out, int out_size, void* d_ws, size_t ws_size,
                              hipStream_t stream) {
  const float* x = (const float*)d_in[0];
  const float* wgt = (const float*)d_in[1];
  const float* bias = (const float*)d_in[2];
  float* out = (float*)d_out;

  uint64_t* wbg = (uint64_t*)d_ws;                                      // 18432 B
  float* bias2 = (float*)((char*)d_ws + IN_CH * 6 * sizeof(uint64_t));  // 49152 B

  cyc_prep<<<IN_CH, 64, 0, stream>>>(wgt, bias, wbg, bias2);
  cyc_main<<<BB * HH, 384, 0, stream>>>(x, wbg, bias2, out);
}

// Round 3
// 210.780 us; speedup vs baseline: 1.8837x; 1.0265x over previous
//
#include <hip/hip_runtime.h>
#include <stdint.h>

// CycleFC 1w1a: out[b,o,h,w] = sum_c sign(x)[b,c,h,w+off(c)] * sign(W)[o,c] + bias[o]
// off(c) = (c+3)%7 - 3, zero-pad OOB. B=64, C=O=384, H=W=32.
//
// Binary-GEMM: pack signs (bit=1 iff <0) into 6 u64 words; out = bias2 - 2*popc(G^WB).
// bias2[o][w] = bias[o] + Nvalid(w) + 2*popc(WB & ~V(w)) precomputed in prep.
// Offsets periodic mod 7; 64%7==1 so mask for offset d in word j is Pm[(d-j) mod 7].
//
// R2: main was latency-bound (VALUBusy 25%, HBM 21%, occ 47%) with 2048 tiny
// blocks. Now 4 h-rows per block (grid 512): weight staging/barriers/ballot
// amortized 4x, LDS weight reads reused across 4 h, 512B-contig loads.

#define IN_CH 384
#define HH 32
#define WW 32
#define BB 64

constexpr uint64_t P7(int t) {
  uint64_t m = 0;
  for (int k = 0; k < 64; ++k)
    if (k % 7 == t) m |= (1ull << k);
  return m;
}
__device__ __constant__ uint64_t Pm[7] = {P7(0), P7(1), P7(2), P7(3), P7(4), P7(5), P7(6)};

// ---------------- prep: one block (1 wave) per output channel o --------------
__global__ __launch_bounds__(64) void cyc_prep(const float* __restrict__ wgt,
                                               const float* __restrict__ bias,
                                               uint64_t* __restrict__ wbg,
                                               float* __restrict__ bias2) {
  const int o = blockIdx.x;
  const int lane = threadIdx.x;
  __shared__ uint64_t wb_sh[6];
#pragma unroll
  for (int j = 0; j < 6; ++j) {
    uint64_t m = __ballot(wgt[o * IN_CH + j * 64 + lane] < 0.0f);
    if (lane == 0) wb_sh[j] = m;
  }
  __syncthreads();
  if (lane < 6) wbg[o * 6 + lane] = wb_sh[lane];
  if (lane < WW) {
    const int w = lane;
    int nv = 0, corr = 0;
#pragma unroll
    for (int j = 0; j < 6; ++j) {
      uint64_t V = 0;
#pragma unroll
      for (int d = -3; d <= 3; ++d) {
        int wd = w + d;
        if (wd >= 0 && wd < WW) V |= Pm[(d - j + 14) % 7];
      }
      nv += __popcll(V);
      corr += __popcll(wb_sh[j] & ~V);
    }
    bias2[o * WW + w] = bias[o] + (float)nv + 2.0f * (float)corr;
  }
}

// ---------------- main: one block per (b, 4-row h-group) ---------------------
#define HR 4  // h rows per block
__global__ __launch_bounds__(384) void cyc_main(const float* __restrict__ x,
                                                const uint64_t* __restrict__ wbg,
                                                const float* __restrict__ bias2,
                                                float* __restrict__ out) {
  __shared__ __align__(16) uint64_t sh_WB[IN_CH * 6];  // 18432 B
  __shared__ uint64_t sh_X[HR][WW][6];                 // 6144 B
  __shared__ uint64_t sh_G[HR][WW][6];                 // 6144 B
  const int t = threadIdx.x;
  const int b = blockIdx.x >> 3;
  const int h0 = (blockIdx.x & 7) * HR;

  // stage packed weights into LDS, float4-vectorized (1152 x 16B)
  {
    const float4* src = reinterpret_cast<const float4*>(wbg);
    float4* dst = reinterpret_cast<float4*>(sh_WB);
#pragma unroll
    for (int i = 0; i < 3; ++i) dst[t + i * 384] = src[t + i * 384];
  }

  // ---- phase 1: each thread owns channel c=t, loads 4 contiguous rows
  // (512 B span), builds 4x 32-bit sign words, ballot-transposes to sh_X.
  const int wave = t >> 6, lane = t & 63;
  const int c = t;
  const float4* xp =
      reinterpret_cast<const float4*>(x + (size_t)((b * IN_CH + c) * HH + h0) * WW);
  unsigned myw[HR];
#pragma unroll
  for (int r = 0; r < HR; ++r) {
    unsigned m = 0;
#pragma unroll
    for (int i = 0; i < 8; ++i) {
      float4 v = xp[r * 8 + i];
      m |= (v.x < 0.0f ? 1u : 0u) << (i * 4 + 0);
      m |= (v.y < 0.0f ? 1u : 0u) << (i * 4 + 1);
      m |= (v.z < 0.0f ? 1u : 0u) << (i * 4 + 2);
      m |= (v.w < 0.0f ? 1u : 0u) << (i * 4 + 3);
    }
    myw[r] = m;
  }
#pragma unroll
  for (int r = 0; r < HR; ++r) {
#pragma unroll
    for (int w = 0; w < WW; ++w) {
      uint64_t m = __ballot((myw[r] >> w) & 1u);
      if (lane == 0) sh_X[r][w][wave] = m;
    }
  }
  __syncthreads();

  // ---- phase 1.5: G[r][w][j] = OR_d (X[r][w+d][j] & Pm[(d-j) mod 7])
#pragma unroll
  for (int k = t; k < HR * WW * 6; k += 384) {
    const int r = k / (WW * 6);
    const int rem = k % (WW * 6);
    const int w = rem & 31, j = rem >> 5;
    uint64_t g = 0;
#pragma unroll
    for (int d = -3; d <= 3; ++d) {
      int wd = w + d;
      if (wd >= 0 && wd < WW) g |= sh_X[r][wd][j] & Pm[(d - j + 14) % 7];
    }
    sh_G[r][w][j] = g;
  }
  __syncthreads();

  // ---- phase 2: 12 og-groups x 32 w lanes; each weight fetch (3x ds_read_b128)
  // serves 4 h rows -> 4 outputs per i per thread.
  const int w = t & 31, og = t >> 5;
  uint64_t g[HR][6];
#pragma unroll
  for (int r = 0; r < HR; ++r)
#pragma unroll
    for (int j = 0; j < 6; ++j) g[r][j] = sh_G[r][w][j];

  float* op = out + (size_t)b * (IN_CH * HH * WW) + (size_t)(og * 32) * (HH * WW) +
              h0 * WW + w;
  const float* bp = bias2 + (og * 32) * WW + w;
  const ulonglong2* wv = reinterpret_cast<const ulonglong2*>(&sh_WB[(og * 32) * 6]);
#pragma unroll 2
  for (int i = 0; i < 32; ++i) {
    ulonglong2 q0 = wv[i * 3 + 0];
    ulonglong2 q1 = wv[i * 3 + 1];
    ulonglong2 q2 = wv[i * 3 + 2];
    float bb = bp[i * WW];
#pragma unroll
    for (int r = 0; r < HR; ++r) {
      int mm = __popcll(g[r][0] ^ q0.x) + __popcll(g[r][1] ^ q0.y) +
               __popcll(g[r][2] ^ q1.x) + __popcll(g[r][3] ^ q1.y) +
               __popcll(g[r][4] ^ q2.x) + __popcll(g[r][5] ^ q2.y);
      op[i * (HH * WW) + r * WW] = bb - 2.0f * (float)mm;
    }
  }
}

extern "C" void kernel_launch(void* const* d_in, const int* in_sizes, int n_in,
                              void* d_out, int out_size, void* d_ws, size_t ws_size,
                              hipStream_t stream) {
  const float* x = (const float*)d_in[0];
  const float* wgt = (const float*)d_in[1];
  const float* bias = (const float*)d_in[2];
  float* out = (float*)d_out;

  uint64_t* wbg = (uint64_t*)d_ws;                                      // 18432 B
  float* bias2 = (float*)((char*)d_ws + IN_CH * 6 * sizeof(uint64_t));  // 49152 B

  cyc_prep<<<IN_CH, 64, 0, stream>>>(wgt, bias, wbg, bias2);
  cyc_main<<<BB * (HH / HR), 384, 0, stream>>>(x, wbg, bias2, out);
}

// Round 4
// 200.150 us; speedup vs baseline: 1.9837x; 1.0531x over previous
//
#include <hip/hip_runtime.h>
#include <stdint.h>

// CycleFC 1w1a: out[b,o,h,w] = sum_c sign(x)[b,c,h,w+off(c)] * sign(W)[o,c] + bias[o]
// off(c) = (c+3)%7 - 3, zero-pad OOB. B=64, C=O=384, H=W=32.
//
// Binary-GEMM: pack signs (bit=1 iff <0) into 6 u64 words; out = bias2 - 2*popc(G^WB).
// bias2[o][w] = bias[o] + Nvalid(w) + 2*popc(WB & ~V(w)) precomputed in prep.
// Offsets periodic mod 7; 64%7==1 so mask for offset d in word j is Pm[(d-j) mod 7].
//
// R3: grid=512 collapsed occupancy to 16% (2 blocks/CU) -> latency-bound at
// VALUBusy 26%. R4 restructure: wave == og-group (32 o-channels); weight
// addresses wave-uniform via readfirstlane -> scalar s_loads (no LDS weight
// stage, no ds_read in the o-loop, one barrier less). Block = (b, 2 h-rows)
// x 768 threads, grid 1024 -> 24 waves/CU. Wave stores 256B contiguous.

#define IN_CH 384
#define HH 32
#define WW 32
#define BB 64
#define HR 2  // h rows per block

constexpr uint64_t P7(int t) {
  uint64_t m = 0;
  for (int k = 0; k < 64; ++k)
    if (k % 7 == t) m |= (1ull << k);
  return m;
}
__device__ __constant__ uint64_t Pm[7] = {P7(0), P7(1), P7(2), P7(3), P7(4), P7(5), P7(6)};

// ---------------- prep: one block (1 wave) per output channel o --------------
__global__ __launch_bounds__(64) void cyc_prep(const float* __restrict__ wgt,
                                               const float* __restrict__ bias,
                                               uint64_t* __restrict__ wbg,
                                               float* __restrict__ bias2) {
  const int o = blockIdx.x;
  const int lane = threadIdx.x;
  __shared__ uint64_t wb_sh[6];
#pragma unroll
  for (int j = 0; j < 6; ++j) {
    uint64_t m = __ballot(wgt[o * IN_CH + j * 64 + lane] < 0.0f);
    if (lane == 0) wb_sh[j] = m;
  }
  __syncthreads();
  if (lane < 6) wbg[o * 6 + lane] = wb_sh[lane];
  if (lane < WW) {
    const int w = lane;
    int nv = 0, corr = 0;
#pragma unroll
    for (int j = 0; j < 6; ++j) {
      uint64_t V = 0;
#pragma unroll
      for (int d = -3; d <= 3; ++d) {
        int wd = w + d;
        if (wd >= 0 && wd < WW) V |= Pm[(d - j + 14) % 7];
      }
      nv += __popcll(V);
      corr += __popcll(wb_sh[j] & ~V);
    }
    bias2[o * WW + w] = bias[o] + (float)nv + 2.0f * (float)corr;
  }
}

// ---------------- main: block = (b, 2 h-rows), 768 threads = 12 waves --------
__global__ __launch_bounds__(768) void cyc_main(const float* __restrict__ x,
                                                const uint64_t* __restrict__ wbg,
                                                const float* __restrict__ bias2,
                                                float* __restrict__ out) {
  __shared__ uint64_t sh_X[HR][WW][6];  // 3072 B
  __shared__ uint64_t sh_G[HR][WW][6];  // 3072 B
  const int t = threadIdx.x;
  const int b = blockIdx.x >> 4;
  const int h0 = (blockIdx.x & 15) * HR;
  const int wave = t >> 6, lane = t & 63;

  // ---- phase 1: wave (j = wave%6, r = wave/6) packs word j of row h0+r.
  // lane owns channel c = j*64+lane: loads its 128B w-row, 32 ballots
  // bit-transpose into sh_X[r][w][j].
  {
    const int j = wave % 6, r = wave / 6;
    const int c = j * 64 + lane;
    const float4* xp = reinterpret_cast<const float4*>(
        x + (size_t)((b * IN_CH + c) * HH + h0 + r) * WW);
    unsigned myw = 0;
#pragma unroll
    for (int i = 0; i < 8; ++i) {
      float4 v = xp[i];
      myw |= (v.x < 0.0f ? 1u : 0u) << (i * 4 + 0);
      myw |= (v.y < 0.0f ? 1u : 0u) << (i * 4 + 1);
      myw |= (v.z < 0.0f ? 1u : 0u) << (i * 4 + 2);
      myw |= (v.w < 0.0f ? 1u : 0u) << (i * 4 + 3);
    }
#pragma unroll
    for (int w = 0; w < WW; ++w) {
      uint64_t m = __ballot((myw >> w) & 1u);
      if (lane == 0) sh_X[r][w][j] = m;
    }
  }
  __syncthreads();

  // ---- phase 1.5: G[r][w][j] = OR_d (X[r][w+d][j] & Pm[(d-j) mod 7])
  if (t < HR * WW * 6) {
    const int r = t / (WW * 6);
    const int q = t % (WW * 6);
    const int w = q & 31, j = q >> 5;
    uint64_t g = 0;
#pragma unroll
    for (int d = -3; d <= 3; ++d) {
      int wd = w + d;
      if (wd >= 0 && wd < WW) g |= sh_X[r][wd][j] & Pm[(d - j + 14) % 7];
    }
    sh_G[r][w][j] = g;
  }
  __syncthreads();

  // ---- phase 2: wave == og-group (32 output channels). lane = (r, w).
  // Weight address wave-uniform -> scalar loads; xor takes SGPR src for free.
  const int og = __builtin_amdgcn_readfirstlane(wave);
  const int w = lane & 31, r = lane >> 5;
  uint64_t g0, g1, g2, g3, g4, g5;
  {
    const ulonglong2* gv = reinterpret_cast<const ulonglong2*>(&sh_G[r][w][0]);
    ulonglong2 a = gv[0], bq = gv[1], cq = gv[2];
    g0 = a.x; g1 = a.y; g2 = bq.x; g3 = bq.y; g4 = cq.x; g5 = cq.y;
  }
  // lanes cover (h0+r)*32+w = h0*32+lane -> 256B contiguous per wave store
  float* op = out + ((size_t)b * IN_CH + og * 32) * (HH * WW) + h0 * WW + lane;
  const uint64_t* wp = wbg + og * 32 * 6;
  const float* bp = bias2 + og * 32 * WW + w;
#pragma unroll 4
  for (int i = 0; i < 32; ++i) {
    const uint64_t w0 = wp[i * 6 + 0], w1 = wp[i * 6 + 1], w2 = wp[i * 6 + 2];
    const uint64_t w3 = wp[i * 6 + 3], w4 = wp[i * 6 + 4], w5 = wp[i * 6 + 5];
    int mm = __popcll(g0 ^ w0) + __popcll(g1 ^ w1) + __popcll(g2 ^ w2) +
             __popcll(g3 ^ w3) + __popcll(g4 ^ w4) + __popcll(g5 ^ w5);
    op[i * (HH * WW)] = bp[i * WW] - 2.0f * (float)mm;
  }
}

extern "C" void kernel_launch(void* const* d_in, const int* in_sizes, int n_in,
                              void* d_out, int out_size, void* d_ws, size_t ws_size,
                              hipStream_t stream) {
  const float* x = (const float*)d_in[0];
  const float* wgt = (const float*)d_in[1];
  const float* bias = (const float*)d_in[2];
  float* out = (float*)d_out;

  uint64_t* wbg = (uint64_t*)d_ws;                                      // 18432 B
  float* bias2 = (float*)((char*)d_ws + IN_CH * 6 * sizeof(uint64_t));  // 49152 B

  cyc_prep<<<IN_CH, 64, 0, stream>>>(wgt, bias, wbg, bias2);
  cyc_main<<<BB * (HH / HR), 768, 0, stream>>>(x, wbg, bias2, out);
}

// Round 5
// 195.619 us; speedup vs baseline: 2.0297x; 1.0232x over previous
//
#include <hip/hip_runtime.h>
#include <stdint.h>

// CycleFC 1w1a: out[b,o,h,w] = sum_c sign(x)[b,c,h,w+off(c)] * sign(W)[o,c] + bias[o]
// off(c) = (c+3)%7 - 3, zero-pad OOB. B=64, C=O=384, H=W=32.
//
// Binary-GEMM: pack signs (bit=1 iff <0) into 6 u64 words; out = bias2 - 2*popc(G^WB).
// bias2t[w][o] = bias[o] + Nvalid(w) + 2*popc(WB & ~V(w)) precomputed in prep.
// Offsets periodic mod 7; 64%7==1 so mask for offset d in word j is Pm[(d-j) mod 7].
//
// R4: wave=og + scalar weight loads -> 74us, VALUBusy 30%: per-iter stall on
// s_load(weights) + vector load(bias2). R5: bias2 transposed and hoisted
// (8x float4 before the loop, zero in-loop vector loads); HR=4 so each weight
// fetch feeds 2 pixel-groups (2x VALU per stall window); full unroll.

#define IN_CH 384
#define HH 32
#define WW 32
#define BB 64
#define HR 4  // h rows per block

constexpr uint64_t P7(int t) {
  uint64_t m = 0;
  for (int k = 0; k < 64; ++k)
    if (k % 7 == t) m |= (1ull << k);
  return m;
}
__device__ __constant__ uint64_t Pm[7] = {P7(0), P7(1), P7(2), P7(3), P7(4), P7(5), P7(6)};

// ---------------- prep: one block (1 wave) per output channel o --------------
__global__ __launch_bounds__(64) void cyc_prep(const float* __restrict__ wgt,
                                               const float* __restrict__ bias,
                                               uint64_t* __restrict__ wbg,
                                               float* __restrict__ bias2t) {
  const int o = blockIdx.x;
  const int lane = threadIdx.x;
  __shared__ uint64_t wb_sh[6];
#pragma unroll
  for (int j = 0; j < 6; ++j) {
    uint64_t m = __ballot(wgt[o * IN_CH + j * 64 + lane] < 0.0f);
    if (lane == 0) wb_sh[j] = m;
  }
  __syncthreads();
  if (lane < 6) wbg[o * 6 + lane] = wb_sh[lane];
  if (lane < WW) {
    const int w = lane;
    int nv = 0, corr = 0;
#pragma unroll
    for (int j = 0; j < 6; ++j) {
      uint64_t V = 0;
#pragma unroll
      for (int d = -3; d <= 3; ++d) {
        int wd = w + d;
        if (wd >= 0 && wd < WW) V |= Pm[(d - j + 14) % 7];
      }
      nv += __popcll(V);
      corr += __popcll(wb_sh[j] & ~V);
    }
    // transposed layout: [w][o] so phase-2 lanes load 32 contiguous floats
    bias2t[w * IN_CH + o] = bias[o] + (float)nv + 2.0f * (float)corr;
  }
}

// ---------------- main: block = (b, 4 h-rows), 768 threads = 12 waves --------
__global__ __launch_bounds__(768) void cyc_main(const float* __restrict__ x,
                                                const uint64_t* __restrict__ wbg,
                                                const float* __restrict__ bias2t,
                                                float* __restrict__ out) {
  __shared__ uint64_t sh_X[HR][WW][6];  // 6144 B
  __shared__ uint64_t sh_G[HR][WW][6];  // 6144 B
  const int t = threadIdx.x;
  const int b = blockIdx.x >> 3;
  const int h0 = (blockIdx.x & 7) * HR;
  const int wave = t >> 6, lane = t & 63;

  // ---- phase 1: 24 (r,j) pack tasks over 12 waves (2 each). Task tau=r*6+j:
  // lane owns channel c=j*64+lane, loads its 128B w-row of row h0+r, 32
  // ballots bit-transpose into sh_X[r][w][j].
#pragma unroll
  for (int p = 0; p < 2; ++p) {
    const int tau = wave + p * 12;
    const int r = tau / 6, j = tau % 6;
    const int c = j * 64 + lane;
    const float4* xp = reinterpret_cast<const float4*>(
        x + (size_t)((b * IN_CH + c) * HH + h0 + r) * WW);
    unsigned myw = 0;
#pragma unroll
    for (int i = 0; i < 8; ++i) {
      float4 v = xp[i];
      myw |= (v.x < 0.0f ? 1u : 0u) << (i * 4 + 0);
      myw |= (v.y < 0.0f ? 1u : 0u) << (i * 4 + 1);
      myw |= (v.z < 0.0f ? 1u : 0u) << (i * 4 + 2);
      myw |= (v.w < 0.0f ? 1u : 0u) << (i * 4 + 3);
    }
#pragma unroll
    for (int w = 0; w < WW; ++w) {
      uint64_t m = __ballot((myw >> w) & 1u);
      if (lane == 0) sh_X[r][w][j] = m;
    }
  }
  __syncthreads();

  // ---- phase 1.5: G[r][w][j] = OR_d (X[r][w+d][j] & Pm[(d-j) mod 7])
  // 768 tasks == 768 threads, one each.
  {
    const int r = t / (WW * 6);
    const int q = t % (WW * 6);
    const int w = q & 31, j = q >> 5;
    uint64_t g = 0;
#pragma unroll
    for (int d = -3; d <= 3; ++d) {
      int wd = w + d;
      if (wd >= 0 && wd < WW) g |= sh_X[r][wd][j] & Pm[(d - j + 14) % 7];
    }
    sh_G[r][w][j] = g;
  }
  __syncthreads();

  // ---- phase 2: wave == og-group (32 output channels). lane = (r2, w) covers
  // rows h0+r2 (group A) and h0+2+r2 (group B): each scalar weight fetch feeds
  // 2 outputs. Bias hoisted: 8x float4 upfront, no vector loads in the loop.
  const int og = __builtin_amdgcn_readfirstlane(wave);
  const int w = lane & 31, r2 = lane >> 5;
  uint64_t gA[6], gB[6];
  {
    const ulonglong2* gv = reinterpret_cast<const ulonglong2*>(&sh_G[r2][w][0]);
    ulonglong2 a0 = gv[0], a1 = gv[1], a2 = gv[2];
    gA[0] = a0.x; gA[1] = a0.y; gA[2] = a1.x; gA[3] = a1.y; gA[4] = a2.x; gA[5] = a2.y;
    const ulonglong2* hv = reinterpret_cast<const ulonglong2*>(&sh_G[2 + r2][w][0]);
    ulonglong2 b0 = hv[0], b1 = hv[1], b2 = hv[2];
    gB[0] = b0.x; gB[1] = b0.y; gB[2] = b1.x; gB[3] = b1.y; gB[4] = b2.x; gB[5] = b2.y;
  }
  float bb[32];
  {
    const float4* bsrc =
        reinterpret_cast<const float4*>(bias2t + w * IN_CH + og * 32);
    float4* bdst = reinterpret_cast<float4*>(bb);
#pragma unroll
    for (int i = 0; i < 8; ++i) bdst[i] = bsrc[i];
  }
  // group A lanes cover (h0+r2)*32+w = h0*32+lane -> 256B contiguous store
  float* opA = out + ((size_t)b * IN_CH + og * 32) * (HH * WW) + h0 * WW + lane;
  float* opB = opA + 2 * WW;
  const uint64_t* wp = wbg + og * 32 * 6;
#pragma unroll
  for (int i = 0; i < 32; ++i) {
    const uint64_t w0 = wp[i * 6 + 0], w1 = wp[i * 6 + 1], w2 = wp[i * 6 + 2];
    const uint64_t w3 = wp[i * 6 + 3], w4 = wp[i * 6 + 4], w5 = wp[i * 6 + 5];
    int mmA = __popcll(gA[0] ^ w0) + __popcll(gA[1] ^ w1) + __popcll(gA[2] ^ w2) +
              __popcll(gA[3] ^ w3) + __popcll(gA[4] ^ w4) + __popcll(gA[5] ^ w5);
    int mmB = __popcll(gB[0] ^ w0) + __popcll(gB[1] ^ w1) + __popcll(gB[2] ^ w2) +
              __popcll(gB[3] ^ w3) + __popcll(gB[4] ^ w4) + __popcll(gB[5] ^ w5);
    opA[i * (HH * WW)] = bb[i] - 2.0f * (float)mmA;
    opB[i * (HH * WW)] = bb[i] - 2.0f * (float)mmB;
  }
}

extern "C" void kernel_launch(void* const* d_in, const int* in_sizes, int n_in,
                              void* d_out, int out_size, void* d_ws, size_t ws_size,
                              hipStream_t stream) {
  const float* x = (const float*)d_in[0];
  const float* wgt = (const float*)d_in[1];
  const float* bias = (const float*)d_in[2];
  float* out = (float*)d_out;

  uint64_t* wbg = (uint64_t*)d_ws;                                       // 18432 B
  float* bias2t = (float*)((char*)d_ws + IN_CH * 6 * sizeof(uint64_t));  // 49152 B

  cyc_prep<<<IN_CH, 64, 0, stream>>>(wgt, bias, wbg, bias2t);
  cyc_main<<<BB * (HH / HR), 768, 0, stream>>>(x, wbg, bias2t, out);
}